// Round 1
// baseline (319.406 us; speedup 1.0000x reference)
//
#include <hip/hip_runtime.h>

// SpatialAttention fp32: B=128, C=3, H=W=256, 8x8 patches, FEAT=192, ENC=16.
// R5: full-residency occupancy push. Grid is exactly 2048 blocks; at
// __launch_bounds__(256,8) all blocks are co-resident (8 blocks/CU x 256 CU),
// removing the 2-round dispatch and doubling latency-hiding waves. The VGPR
// cap at 8 blocks/CU is 64, so peak register liveness is restructured:
//  - encoder partials stream to LDS as computed (1 acc live, not 16)
//  - decoder runs in two e-halves; h[8..15] staged in LDS hl[8][64]
//    (all 4 waves write bit-identical values -> benign duplicate writes,
//     reload is same-lane so only lgkmcnt orders it, no extra barrier)
// Peak liveness: enc ~56 (xv48+temps), dec ~60 (o48+h8+temps). No extra FMAs.
// LDS 19456 B (pad-257 dropped: both access patterns are lane-consecutive,
// conflict-free without it); 8 x 19456 = 156 KB <= 160 KB/CU.

constexpr int NPATCH = 128 * 32 * 32;
constexpr float L2E  = 1.4426950408889634f;

__global__ __launch_bounds__(256, 8) void spatial_attn(
    const float* __restrict__ x,      // [128][3][256][256]
    const float* __restrict__ Wenc,   // [16][192]
    const float* __restrict__ benc,   // [16]
    const float* __restrict__ Wdec,   // [192][16]
    const float* __restrict__ bdec,   // [192]
    float* __restrict__ y)            // [128][3][256][256]
{
  __shared__ float encl[16 * 256];    // [e][tid] encoder partials
  __shared__ float hl[8 * 64];        // staged relu(h[8..15]) per patch-lane
  __shared__ float sls[256];          // softmax partial sums

  const int tid  = threadIdx.x;
  const int lane = tid & 63;
  const int wv   = __builtin_amdgcn_readfirstlane(tid >> 6);  // provably uniform
  const int p    = blockIdx.x * 64 + lane;                    // one patch per lane
  const int b    = p >> 10;
  const int ii   = (p >> 5) & 31;
  const int jj   = p & 31;
  const size_t base = (size_t)b * 196608 + (size_t)ii * 2048 + (size_t)jj * 8;

  // ---- Load this wave's 48 features (rows 6wv..6wv+5), coalesced float4 ----
  float xv[48];
  #pragma unroll
  for (int t = 0; t < 6; ++t) {
    const int cr = 6 * wv + t;
    const float* src = x + base + (cr >> 3) * 65536 + (cr & 7) * 256;
    const float4 v0 = *(const float4*)(src);
    const float4 v1 = *(const float4*)(src + 4);
    xv[t*8+0]=v0.x; xv[t*8+1]=v0.y; xv[t*8+2]=v0.z; xv[t*8+3]=v0.w;
    xv[t*8+4]=v1.x; xv[t*8+5]=v1.y; xv[t*8+6]=v1.z; xv[t*8+7]=v1.w;
  }

  // ---- Encoder partial over 48 features; stream each acc[e] to LDS ----
  #pragma unroll
  for (int e = 0; e < 16; ++e) {
    const float* w = Wenc + e * 192 + wv * 48;   // wave-uniform -> s_load
    float a = 0.0f;
    #pragma unroll
    for (int q = 0; q < 48; ++q) a = fmaf(w[q], xv[q], a);
    encl[e * 256 + tid] = a;                     // only one acc live at a time
  }
  __syncthreads();

  // ---- Cross-wave reduce. e=8..15 first -> stage relu'd h in LDS.
  //      All 4 waves compute/write identical values: benign duplicate write.
  #pragma unroll
  for (int e = 8; e < 16; ++e) {
    const float a = encl[e*256 + lane]       + encl[e*256 + 64  + lane]
                  + encl[e*256 + 128 + lane] + encl[e*256 + 192 + lane];
    hl[(e - 8) * 64 + lane] = fmaxf(a + benc[e], 0.0f);
  }
  float h[8];
  #pragma unroll
  for (int e = 0; e < 8; ++e) {
    const float a = encl[e*256 + lane]       + encl[e*256 + 64  + lane]
                  + encl[e*256 + 128 + lane] + encl[e*256 + 192 + lane];
    h[e] = fmaxf(a + benc[e], 0.0f);
  }

  // ---- Decoder pass A: accumulate o[48] over e=0..7 (h[0..7] in regs) ----
  float o[48];
  #pragma unroll
  for (int q = 0; q < 48; ++q) {
    const int f = wv * 48 + q;
    const float* w = Wdec + f * 16;              // wave-uniform -> s_load
    float v = bdec[f];
    #pragma unroll
    for (int e = 0; e < 8; ++e) v = fmaf(w[e], h[e], v);
    o[q] = v;                                    // partial, no relu yet
  }

  // ---- Swap in the staged half (same-lane readback; lgkmcnt orders it) ----
  #pragma unroll
  for (int e = 0; e < 8; ++e) h[e] = hl[e * 64 + lane];

  // ---- Decoder pass B: finish over e=8..15, relu, softmax partial sum ----
  float s = 0.0f;
  #pragma unroll
  for (int q = 0; q < 48; ++q) {
    const int f = wv * 48 + q;
    const float* w = Wdec + f * 16 + 8;
    float v = o[q];
    #pragma unroll
    for (int e = 0; e < 8; ++e) v = fmaf(w[e], h[e], v);
    v = fmaxf(v, 0.0f);
    o[q] = v;
    s += __builtin_amdgcn_exp2f(v * L2E);        // out>=0, bounded: no max-sub
  }

  // ---- Softmax denominator across the 4 waves ----
  sls[tid] = s;
  __syncthreads();
  const float st = sls[lane] + sls[lane + 64] + sls[lane + 128] + sls[lane + 192];
  const float inv = __builtin_amdgcn_rcpf(st);

  // ---- y = softmax(out)*out, coalesced float4 stores ----
  #pragma unroll
  for (int t = 0; t < 6; ++t) {
    const int cr = 6 * wv + t;
    float* dst = y + base + (cr >> 3) * 65536 + (cr & 7) * 256;
    float r[8];
    #pragma unroll
    for (int c = 0; c < 8; ++c) {
      const float ov = o[t * 8 + c];
      r[c] = __builtin_amdgcn_exp2f(ov * L2E) * inv * ov;
    }
    const float4 s0 = {r[0], r[1], r[2], r[3]};
    const float4 s1 = {r[4], r[5], r[6], r[7]};
    *(float4*)(dst)     = s0;
    *(float4*)(dst + 4) = s1;
  }
}

extern "C" void kernel_launch(void* const* d_in, const int* in_sizes, int n_in,
                              void* d_out, int out_size, void* d_ws, size_t ws_size,
                              hipStream_t stream) {
  const float* x    = (const float*)d_in[0];
  const float* Wenc = (const float*)d_in[1];
  const float* benc = (const float*)d_in[2];
  const float* Wdec = (const float*)d_in[3];
  const float* bdec = (const float*)d_in[4];
  float* y = (float*)d_out;
  dim3 grid(NPATCH / 64), block(256);
  hipLaunchKernelGGL(spatial_attn, grid, block, 0, stream, x, Wenc, benc, Wdec, bdec, y);
}

// Round 2
// 202.996 us; speedup vs baseline: 1.5735x; 1.5735x over previous
//
#include <hip/hip_runtime.h>

// SpatialAttention fp32: B=128, C=3, H=W=256, 8x8 patches, FEAT=192, ENC=16.
// R6: occupancy push, spill-safe this time. R5 (launch_bounds(256,8), 48
// features/wave) hit the VGPR cap 64 with ~70 peak liveness -> allocator
// dumped xv[48]/o[48] to scratch (VGPR_Count=32, WRITE_SIZE 98->355 MB,
// 262 us). R6 halves per-thread arrays instead: 512-thread blocks, 8 waves,
// each wave owns 24 features (3 rows) of the same 64 patches.
//   peak liveness: encoder xv[24]+temps ~35; decoder o[24]+h[16]+temps ~48
//   -> fits the 64-VGPR cap with ~15 margin.
// Weight chunk index stays wave-uniform (wv*24) -> s_load/constant path
// (per-lane weight VMEM was the R3 288us regression). LDS 34.8 KB/block ->
// 4 blocks/CU = 32 waves/CU (100%); grid 2048 blocks -> 2 full-occupancy
// rounds. Spill tripwire for the post-mortem: WRITE_SIZE must be ~98 MB.

constexpr int NPATCH = 128 * 32 * 32;
constexpr float L2E  = 1.4426950408889634f;

__global__ __launch_bounds__(512, 8) void spatial_attn(
    const float* __restrict__ x,      // [128][3][256][256]
    const float* __restrict__ Wenc,   // [16][192]
    const float* __restrict__ benc,   // [16]
    const float* __restrict__ Wdec,   // [192][16]
    const float* __restrict__ bdec,   // [192]
    float* __restrict__ y)            // [128][3][256][256]
{
  __shared__ float encl[16 * 512];    // [e][tid] encoder partials
  __shared__ float sls[512];          // softmax partial sums

  const int tid  = threadIdx.x;
  const int lane = tid & 63;
  const int wv   = __builtin_amdgcn_readfirstlane(tid >> 6);  // provably uniform
  const int p    = blockIdx.x * 64 + lane;                    // one patch per lane
  const int b    = p >> 10;
  const int ii   = (p >> 5) & 31;
  const int jj   = p & 31;
  const size_t base = (size_t)b * 196608 + (size_t)ii * 2048 + (size_t)jj * 8;

  // ---- Load this wave's 24 features (rows 3wv..3wv+2), coalesced float4 ----
  float xv[24];
  #pragma unroll
  for (int t = 0; t < 3; ++t) {
    const int cr = 3 * wv + t;
    const float* src = x + base + (cr >> 3) * 65536 + (cr & 7) * 256;
    const float4 v0 = *(const float4*)(src);
    const float4 v1 = *(const float4*)(src + 4);
    xv[t*8+0]=v0.x; xv[t*8+1]=v0.y; xv[t*8+2]=v0.z; xv[t*8+3]=v0.w;
    xv[t*8+4]=v1.x; xv[t*8+5]=v1.y; xv[t*8+6]=v1.z; xv[t*8+7]=v1.w;
  }

  // ---- Encoder partial over 24 features; stream each acc[e] to LDS ----
  #pragma unroll
  for (int e = 0; e < 16; ++e) {
    const float* w = Wenc + e * 192 + wv * 24;   // wave-uniform -> s_load
    float a = 0.0f;
    #pragma unroll
    for (int q = 0; q < 24; ++q) a = fmaf(w[q], xv[q], a);
    encl[e * 512 + tid] = a;                     // one acc live at a time
  }
  __syncthreads();

  // ---- Cross-wave reduce (8 partials per e), bias + relu ----
  float h[16];
  #pragma unroll
  for (int e = 0; e < 16; ++e) {
    const float* c = encl + e * 512 + lane;
    float a = c[0];
    #pragma unroll
    for (int w8 = 1; w8 < 8; ++w8) a += c[w8 * 64];
    h[e] = fmaxf(a + benc[e], 0.0f);
  }

  // ---- Decoder: this wave's 24 outputs, kept in registers ----
  float o[24];
  float s = 0.0f;
  #pragma unroll
  for (int q = 0; q < 24; ++q) {
    const int f = wv * 24 + q;
    const float* w = Wdec + f * 16;              // wave-uniform -> s_load
    float v = bdec[f];
    #pragma unroll
    for (int e = 0; e < 16; ++e) v = fmaf(w[e], h[e], v);
    v = fmaxf(v, 0.0f);
    o[q] = v;
    s += __builtin_amdgcn_exp2f(v * L2E);        // out>=0, bounded: no max-sub
  }

  // ---- Softmax denominator across the 8 waves ----
  sls[tid] = s;
  __syncthreads();
  float st = sls[lane];
  #pragma unroll
  for (int w8 = 1; w8 < 8; ++w8) st += sls[w8 * 64 + lane];
  const float inv = __builtin_amdgcn_rcpf(st);

  // ---- y = softmax(out)*out, coalesced float4 stores ----
  #pragma unroll
  for (int t = 0; t < 3; ++t) {
    const int cr = 3 * wv + t;
    float* dst = y + base + (cr >> 3) * 65536 + (cr & 7) * 256;
    float r[8];
    #pragma unroll
    for (int c = 0; c < 8; ++c) {
      const float ov = o[t * 8 + c];
      r[c] = __builtin_amdgcn_exp2f(ov * L2E) * inv * ov;
    }
    const float4 s0 = {r[0], r[1], r[2], r[3]};
    const float4 s1 = {r[4], r[5], r[6], r[7]};
    *(float4*)(dst)     = s0;
    *(float4*)(dst + 4) = s1;
  }
}

extern "C" void kernel_launch(void* const* d_in, const int* in_sizes, int n_in,
                              void* d_out, int out_size, void* d_ws, size_t ws_size,
                              hipStream_t stream) {
  const float* x    = (const float*)d_in[0];
  const float* Wenc = (const float*)d_in[1];
  const float* benc = (const float*)d_in[2];
  const float* Wdec = (const float*)d_in[3];
  const float* bdec = (const float*)d_in[4];
  float* y = (float*)d_out;
  dim3 grid(NPATCH / 64), block(512);
  hipLaunchKernelGGL(spatial_attn, grid, block, 0, stream, x, Wenc, benc, Wdec, bdec, y);
}